// Round 19
// baseline (115.612 us; speedup 1.0000x reference)
//
#include <hip/hip_runtime.h>
#include <hip/hip_bf16.h>

#define EMB  1024
#define VIN  512
#define VOUT 1024
#define NH   16
#define DH   64
#define BB   8
#define LQ   512
#define LK   1024

typedef __attribute__((ext_vector_type(8))) short bf16x8;
typedef __attribute__((ext_vector_type(4))) float f32x4;

typedef const __attribute__((address_space(1))) unsigned int* gptr_t;
typedef __attribute__((address_space(3))) unsigned int* lptr_t;

__device__ __forceinline__ unsigned short f2bf(float x) {
    unsigned int u = __float_as_uint(x);
    u += 0x7FFF + ((u >> 16) & 1);   // RN-even
    return (unsigned short)(u >> 16);
}
__device__ __forceinline__ float bf2f(unsigned short h) {
    return __uint_as_float(((unsigned int)h) << 16);
}
__device__ __forceinline__ float fexp2(float x) {
    return __builtin_amdgcn_exp2f(x);
}
__device__ __forceinline__ unsigned int pk2bf(float a, float b) {
    float2 f; f.x = a; f.y = b;
    __hip_bfloat162 t = __float22bfloat162_rn(f);   // v_cvt_pk_bf16_f32 (RNE)
    return *reinterpret_cast<unsigned int*>(&t);
}

#define SWZ(row, cb)   (((row) << 7) + ((cb) ^ (((row) & 7) << 4)))
#define SWZ32(row, cb) (((row) << 6) + ((cb) ^ (((row) & 3) << 4)))

// ---------------------------------------------------------------------------
// Fused conversion: blocks 0..12287 = q/k/v fp32->bf16 planes;
// blocks 12288..15359 = weight transpose-split tiles (Wq/Wk/Wv hi; Wo hi+lo).
// ---------------------------------------------------------------------------
__device__ __forceinline__ void wtile(const float* W, unsigned short* Wht,
                                      unsigned short* Wlt, int K, int N,
                                      int bx, int by, int tx, int ty)
{
    __shared__ float t[32][33];
    const int n0 = bx * 32, k0 = by * 32;
#pragma unroll
    for (int r = 0; r < 32; r += 8)
        t[ty + r][tx] = W[(size_t)(k0 + ty + r) * N + n0 + tx];
    __syncthreads();
#pragma unroll
    for (int r = 0; r < 32; r += 8) {
        float x = t[tx][ty + r];
        unsigned short h = f2bf(x);
        size_t o = (size_t)(n0 + ty + r) * K + k0 + tx;
        Wht[o] = h;
        if (Wlt) Wlt[o] = f2bf(x - bf2f(h));
    }
}

__global__ __launch_bounds__(256) void convert_all(const float* __restrict__ q,
                                                   const float* __restrict__ k,
                                                   const float* __restrict__ v,
                                                   const float* __restrict__ Wq,
                                                   const float* __restrict__ Wk,
                                                   const float* __restrict__ Wv,
                                                   const float* __restrict__ Wo,
                                                   unsigned short* __restrict__ Aq,
                                                   unsigned short* __restrict__ Ak,
                                                   unsigned short* __restrict__ Av,
                                                   unsigned short* __restrict__ Wqt,
                                                   unsigned short* __restrict__ Wkt,
                                                   unsigned short* __restrict__ Wvt,
                                                   unsigned short* __restrict__ Woh,
                                                   unsigned short* __restrict__ Wol)
{
    const int id = blockIdx.x;
    if (id < 12288) {
        const int which = id >> 12;
        const float* in = (which == 0) ? q : (which == 1) ? k : v;
        unsigned short* out = (which == 0) ? Aq : (which == 1) ? Ak : Av;
        const int i = (id & 4095) * 256 + threadIdx.x;
        float val[4];
        *reinterpret_cast<float4*>(val) = *reinterpret_cast<const float4*>(&in[(size_t)i * 4]);
        unsigned short h[4];
#pragma unroll
        for (int j = 0; j < 4; ++j) h[j] = f2bf(val[j]);
        *reinterpret_cast<uint2*>(&out[(size_t)i * 4]) = *reinterpret_cast<uint2*>(h);
    } else {
        const int wid = id - 12288;
        const int tx = threadIdx.x & 31, ty = threadIdx.x >> 5;
        if (wid < 1024)      wtile(Wq, Wqt, nullptr, 1024, 1024, wid & 31, wid >> 5, tx, ty);
        else if (wid < 1536) wtile(Wk, Wkt, nullptr, 512, 1024, (wid - 1024) & 31, (wid - 1024) >> 5, tx, ty);
        else if (wid < 2048) wtile(Wv, Wvt, nullptr, 512, 1024, (wid - 1536) & 31, (wid - 1536) >> 5, tx, ty);
        else                 wtile(Wo, Woh, Wol, 1024, 1024, (wid - 2048) & 31, (wid - 2048) >> 5, tx, ty);
    }
}

// ---------------------------------------------------------------------------
// Stage 64x64 of a bf16 plane via global_load_lds (pre-swizzled source).
// ---------------------------------------------------------------------------
__device__ __forceinline__ void stagehalf(const unsigned short* g0, int Kstride,
                                          unsigned short* l0, int lane)
{
#pragma unroll
    for (int r = 0; r < 8; ++r) {
        int row  = r * 8 + (lane >> 3);
        int colb = ((lane & 7) << 4) ^ ((row & 7) << 4);
        const unsigned short* src = g0 + (size_t)row * Kstride + (colb >> 1);
        __builtin_amdgcn_global_load_lds((gptr_t)src, (lptr_t)(l0 + r * 512), 16, 0, 0);
    }
}

// ---------------------------------------------------------------------------
// Fused Q/K/V projection GEMM (plain bf16, double-buffered LDS), one launch.
// seg0: Q (K=1024, out scaled 0.125*log2e); seg1: K; seg2: V transposed.
// seg0/seg1 epilogue via LDS -> coalesced uint4 stores.
// ---------------------------------------------------------------------------
__global__ __launch_bounds__(256, 2) void gemm_qkv(const unsigned short* __restrict__ Aq,
                                                   const unsigned short* __restrict__ Ak,
                                                   const unsigned short* __restrict__ Av,
                                                   const unsigned short* __restrict__ Wqt,
                                                   const unsigned short* __restrict__ Wkt,
                                                   const unsigned short* __restrict__ Wvt,
                                                   const float* __restrict__ bq,
                                                   const float* __restrict__ bk,
                                                   const float* __restrict__ bv,
                                                   unsigned short* __restrict__ Qh,
                                                   unsigned short* __restrict__ Kh,
                                                   unsigned short* __restrict__ Vth)
{
    __shared__ unsigned short As[2][128 * 64], Bs[2][128 * 64];

    const int id  = blockIdx.x;
    const int seg = (id < 256) ? 0 : (id < 768) ? 1 : 2;
    const int lid = id - ((seg == 0) ? 0 : (seg == 1) ? 256 : 768);
    const int nwg = (seg == 0) ? 256 : 512;
    const int K   = (seg == 0) ? 1024 : 512;
    const unsigned short* Ah  = (seg == 0) ? Aq : (seg == 1) ? Ak : Av;
    const unsigned short* Bht = (seg == 0) ? Wqt : (seg == 1) ? Wkt : Wvt;
    const float* bias = (seg == 0) ? bq : (seg == 1) ? bk : bv;
    unsigned short* Ch = (seg == 0) ? Qh : (seg == 1) ? Kh : Vth;
    const int N = 1024;

    const int qq  = nwg >> 3;
    const int swz = (lid & 7) * qq + (lid >> 3);   // seg-local XCD swizzle
    const int bx = swz & 7, by = swz >> 3;         // nbx = 8
    const int m0 = by * 128, n0 = bx * 128;

    const int tid  = threadIdx.x;
    const int lane = tid & 63;
    const int w    = tid >> 6;
    const int wm = (w & 1) * 64;
    const int wn = (w >> 1) * 64;
    const int lr = lane & 15;
    const int lk = lane >> 4;

    f32x4 acc[4][4];
#pragma unroll
    for (int i = 0; i < 4; ++i)
#pragma unroll
        for (int j = 0; j < 4; ++j) acc[i][j] = (f32x4)(0.f);

    const unsigned short* mysrc = (w < 2)
        ? Ah  + (size_t)(m0 + (w & 1) * 64) * K
        : Bht + (size_t)(n0 + (w & 1) * 64) * K;
    const int lofs = (w & 1) * 4096;
    unsigned short* pl0 = ((w < 2) ? As[0] : Bs[0]) + lofs;
    unsigned short* pl1 = ((w < 2) ? As[1] : Bs[1]) + lofs;

    stagehalf(mysrc, K, pl0, lane);

    const int nt = K >> 6;
    for (int t = 0; t < nt; ++t) {
        __syncthreads();
        if (t + 1 < nt)
            stagehalf(mysrc + ((size_t)(t + 1) << 6), K, ((t & 1) ? pl0 : pl1), lane);

        const char* Ac = (const char*)As[t & 1];
        const char* Bc = (const char*)Bs[t & 1];
#pragma unroll
        for (int ks = 0; ks < 2; ++ks) {
            bf16x8 ah[4], bh[4];
            const int cb = ks * 64 + lk * 16;
#pragma unroll
            for (int f = 0; f < 4; ++f) {
                ah[f] = *reinterpret_cast<const bf16x8*>(Ac + SWZ(wm + f * 16 + lr, cb));
                bh[f] = *reinterpret_cast<const bf16x8*>(Bc + SWZ(wn + f * 16 + lr, cb));
            }
#pragma unroll
            for (int fm = 0; fm < 4; ++fm)
#pragma unroll
                for (int fn = 0; fn < 4; ++fn)
                    acc[fm][fn] = __builtin_amdgcn_mfma_f32_16x16x32_bf16(ah[fm], bh[fn], acc[fm][fn], 0, 0, 0);
        }
    }

    if (seg != 2) {
        // -------- LDS-transpose epilogue: coalesced uint4 stores ----------
        __syncthreads();   // compute done; reuse staging LDS
        const float sc = (seg == 0) ? 0.18033688011112042f : 1.0f;
#pragma unroll
        for (int fn = 0; fn < 4; ++fn) {
            const int col = wn + fn * 16 + lr;
            const float bv_ = bias[n0 + col];
#pragma unroll
            for (int fm = 0; fm < 4; ++fm) {
                const int row0 = wm + fm * 16 + lk * 4;
#pragma unroll
                for (int r = 0; r < 4; ++r) {
                    int row = row0 + r;
                    unsigned short* base = (row < 64) ? ((row < 32) ? As[0] : As[1])
                                                      : ((row < 96) ? Bs[0] : Bs[1]);
                    base[(row & 31) * 136 + col] = f2bf((acc[fm][fn][r] + bv_) * sc);
                }
            }
        }
        __syncthreads();
#pragma unroll
        for (int rnd = 0; rnd < 8; ++rnd) {
            int flat = rnd * 256 + tid;
            int row  = flat >> 4;
            int c16  = flat & 15;
            const unsigned short* base = (row < 64) ? ((row < 32) ? As[0] : As[1])
                                                    : ((row < 96) ? Bs[0] : Bs[1]);
            uint4 vv = *reinterpret_cast<const uint4*>(&base[(row & 31) * 136 + c16 * 8]);
            *reinterpret_cast<uint4*>(&Ch[(size_t)(m0 + row) * N + n0 + c16 * 8]) = vv;
        }
    } else {
        // -------- V: per-head transposed, already 8B-packed ----------------
#pragma unroll
        for (int fn = 0; fn < 4; ++fn) {
            const int col = n0 + wn + fn * 16 + lr;
            const float bv_ = bias[col];
#pragma unroll
            for (int fm = 0; fm < 4; ++fm) {
                const int row0 = m0 + wm + fm * 16 + lk * 4;
                unsigned short h4[4];
#pragma unroll
                for (int r = 0; r < 4; ++r)
                    h4[r] = f2bf(acc[fm][fn][r] + bv_);
                size_t o = (((size_t)((row0 >> 10) * NH + (col >> 6)) * 64 + (col & 63)) << 10) + (row0 & 1023);
                *reinterpret_cast<uint2*>(&Ch[o]) = *reinterpret_cast<uint2*>(h4);
            }
        }
    }
}

// ---------------------------------------------------------------------------
// Stage one 128-row x 32-col plane tile (gemm2, BK=32). Source pre-XOR'd with
// SWZ32's involution (16B-granular), LDS dest linear per rule #21.
// ---------------------------------------------------------------------------
__device__ __forceinline__ void stageplane32(const unsigned short* g0, int Kstride,
                                             unsigned short* l0, int lane)
{
#pragma unroll
    for (int r = 0; r < 8; ++r) {
        int row  = r * 16 + (lane >> 2);
        int colb = ((lane & 3) << 4) ^ ((row & 3) << 4);
        const unsigned short* src = g0 + (size_t)row * Kstride + (colb >> 1);
        __builtin_amdgcn_global_load_lds((gptr_t)src, (lptr_t)(l0 + r * 512), 16, 0, 0);
    }
}

// ---------------------------------------------------------------------------
// Split-bf16 MFMA GEMM (3 products) — O-projection, fp32 out.
// R19: BK=32 double-buffered -> 64KB LDS -> 2 blocks/CU (was 128KB, 1/CU).
// ---------------------------------------------------------------------------
__global__ __launch_bounds__(256, 2) void gemm2(const unsigned short* __restrict__ Ah,
                                                const unsigned short* __restrict__ Al,
                                                const unsigned short* __restrict__ Bht,
                                                const unsigned short* __restrict__ Blt,
                                                const float* __restrict__ bias,
                                                float* __restrict__ C,
                                                int M, int N, int K)
{
    __shared__ unsigned short As_h[2][128 * 32], As_l[2][128 * 32];
    __shared__ unsigned short Bs_h[2][128 * 32], Bs_l[2][128 * 32];

    const int nbx = N >> 7;
    const int nwg = gridDim.x;
    const int qq  = nwg >> 3;
    const int id  = blockIdx.x;
    const int swz = (id & 7) * qq + (id >> 3);
    const int bx = swz % nbx, by = swz / nbx;
    const int m0 = by * 128, n0 = bx * 128;

    const int tid  = threadIdx.x;
    const int lane = tid & 63;
    const int w    = tid >> 6;
    const int wm = (w & 1) * 64;
    const int wn = (w >> 1) * 64;
    const int lr = lane & 15;
    const int lk = lane >> 4;

    f32x4 acc[4][4];
#pragma unroll
    for (int i = 0; i < 4; ++i)
#pragma unroll
        for (int j = 0; j < 4; ++j) acc[i][j] = (f32x4)(0.f);

    const unsigned short* mysrc =
        (w == 0) ? Ah + (size_t)m0 * K :
        (w == 1) ? Al + (size_t)m0 * K :
        (w == 2) ? Bht + (size_t)n0 * K :
                   Blt + (size_t)n0 * K;
    unsigned short* pl0 = (w == 0) ? As_h[0] : (w == 1) ? As_l[0] : (w == 2) ? Bs_h[0] : Bs_l[0];
    unsigned short* pl1 = (w == 0) ? As_h[1] : (w == 1) ? As_l[1] : (w == 2) ? Bs_h[1] : Bs_l[1];

    stageplane32(mysrc, K, pl0, lane);

    const int nt = K >> 5;   // BK = 32
    for (int t = 0; t < nt; ++t) {
        __syncthreads();
        if (t + 1 < nt)
            stageplane32(mysrc + ((size_t)(t + 1) << 5), K, ((t & 1) ? pl0 : pl1), lane);

        const char* Ahc = (const char*)As_h[t & 1];
        const char* Alc = (const char*)As_l[t & 1];
        const char* Bhc = (const char*)Bs_h[t & 1];
        const char* Blc = (const char*)Bs_l[t & 1];
        {
            bf16x8 ah[4], al[4], bh[4], bl[4];
            const int cb = lk * 16;
#pragma unroll
            for (int f = 0; f < 4; ++f) {
                int rowA = wm + f * 16 + lr;
                ah[f] = *reinterpret_cast<const bf16x8*>(Ahc + SWZ32(rowA, cb));
                al[f] = *reinterpret_cast<const bf16x8*>(Alc + SWZ32(rowA, cb));
                int rowB = wn + f * 16 + lr;
                bh[f] = *reinterpret_cast<const bf16x8*>(Bhc + SWZ32(rowB, cb));
                bl[f] = *reinterpret_cast<const bf16x8*>(Blc + SWZ32(rowB, cb));
            }
#pragma unroll
            for (int fm = 0; fm < 4; ++fm)
#pragma unroll
                for (int fn = 0; fn < 4; ++fn) {
                    acc[fm][fn] = __builtin_amdgcn_mfma_f32_16x16x32_bf16(ah[fm], bh[fn], acc[fm][fn], 0, 0, 0);
                    acc[fm][fn] = __builtin_amdgcn_mfma_f32_16x16x32_bf16(ah[fm], bl[fn], acc[fm][fn], 0, 0, 0);
                    acc[fm][fn] = __builtin_amdgcn_mfma_f32_16x16x32_bf16(al[fm], bh[fn], acc[fm][fn], 0, 0, 0);
                }
        }
    }

#pragma unroll
    for (int fn = 0; fn < 4; ++fn) {
        const int col = n0 + wn + fn * 16 + lr;
        const float bv = bias[col];
#pragma unroll
        for (int fm = 0; fm < 4; ++fm) {
            const int row0 = m0 + wm + fm * 16 + lk * 4;
#pragma unroll
            for (int r = 0; r < 4; ++r)
                C[(size_t)(row0 + r) * N + col] = acc[fm][fn][r] + bv;
        }
    }
}

// ---------------------------------------------------------------------------
// Stage 32 rows x 128B (row stride 1024 elems), pre-swizzled source.
// ---------------------------------------------------------------------------
__device__ __forceinline__ void stage32(const unsigned short* g0, unsigned short* l0, int lane)
{
#pragma unroll
    for (int r = 0; r < 4; ++r) {
        int row  = r * 8 + (lane >> 3);
        int colb = ((lane & 7) << 4) ^ ((row & 7) << 4);
        const unsigned short* src = g0 + ((size_t)row << 10) + (colb >> 1);
        __builtin_amdgcn_global_load_lds((gptr_t)src, (lptr_t)(l0 + r * 512), 16, 0, 0);
    }
}

// ---------------------------------------------------------------------------
// MFMA flash attention (R18 + m init 0: tile-0 rescale never fires; rescale
// path retained for safety).
// ---------------------------------------------------------------------------
__global__ __launch_bounds__(256, 4) void attn_mfma(const unsigned short* __restrict__ Qh,
                                                    const unsigned short* __restrict__ Kh,
                                                    const unsigned short* __restrict__ Vth,
                                                    unsigned short* __restrict__ Ch,
                                                    unsigned short* __restrict__ Cl)
{
    const int id  = blockIdx.x;
    const int qt  = (id >> 3) & 7;
    const int grp = (id & 7) | ((id >> 6) << 3);   // 0..127, same-XCD groups
    const int h = grp & 15, b = grp >> 4;

    const int tid  = threadIdx.x;
    const int lane = tid & 63;
    const int w    = tid >> 6;
    const int lr   = lane & 15;
    const int lk   = lane >> 4;

    __shared__ unsigned short KVs[2][2][4096];
    __shared__ unsigned short Ps[4][1024];

    bf16x8 qb[2];
    {
        const unsigned short* qrow = &Qh[(size_t)(b * LQ + qt * 64 + w * 16 + lr) * EMB + h * DH];
        qb[0] = *reinterpret_cast<const bf16x8*>(qrow + lk * 8);
        qb[1] = *reinterpret_cast<const bf16x8*>(qrow + 32 + lk * 8);
    }

    const unsigned short* K0 = Kh + ((size_t)(b * LK) << 10) + h * DH;
    const unsigned short* V0 = Vth + ((size_t)(grp * 64) << 10);

    {
        const int half = (w & 1) * 32;
        if (w < 2) stage32(K0 + ((size_t)half << 10), KVs[0][0] + half * 64, lane);
        else       stage32(V0 + ((size_t)half << 10), KVs[0][1] + half * 64, lane);
    }

    float m = 0.f, lsum = 0.f;   // m=0 init: safe (rescale path retained)
    f32x4 acc[4];
#pragma unroll
    for (int f = 0; f < 4; ++f) acc[f] = (f32x4)(0.f);

    for (int kt = 0; kt < LK / 64; ++kt) {
        const int cur = kt & 1;
        __syncthreads();

        if (kt + 1 < LK / 64) {
            const size_t koff = (size_t)(kt + 1) * 64;
            const int half = (w & 1) * 32;
            if (w < 2) stage32(K0 + ((koff + half) << 10), KVs[cur ^ 1][0] + half * 64, lane);
            else       stage32(V0 + ((size_t)half << 10) + koff, KVs[cur ^ 1][1] + half * 64, lane);
        }

        const char* Ks = (const char*)KVs[cur][0];
        const char* Vs = (const char*)KVs[cur][1];

        f32x4 s[4];
#pragma unroll
        for (int fn = 0; fn < 4; ++fn) s[fn] = (f32x4)(0.f);
        __builtin_amdgcn_s_setprio(1);
#pragma unroll
        for (int ks = 0; ks < 2; ++ks) {
            const int cb = ks * 64 + lk * 16;
#pragma unroll
            for (int fn = 0; fn < 4; ++fn) {
                bf16x8 kb = *reinterpret_cast<const bf16x8*>(Ks + SWZ(fn * 16 + lr, cb));
                s[fn] = __builtin_amdgcn_mfma_f32_16x16x32_bf16(kb, qb[ks], s[fn], 0, 0, 0);
            }
        }
        __builtin_amdgcn_s_setprio(0);

        // online softmax, lane-local row q = lr; gated defer-max (THR=8)
        {
            f32x4 t4 = s[0];
#pragma unroll
            for (int fn = 1; fn < 4; ++fn)
#pragma unroll
                for (int r = 0; r < 4; ++r) t4[r] = fmaxf(t4[r], s[fn][r]);
            float lmx = fmaxf(fmaxf(t4[0], t4[1]), fmaxf(t4[2], t4[3]));

            if (!__all(lmx <= m + 8.f)) {
                float mx = fmaxf(lmx, __shfl_xor(lmx, 16));
                mx = fmaxf(mx, __shfl_xor(mx, 32));
                float mnew = fmaxf(m, mx);
                float corr = fexp2(m - mnew);
                m = mnew;
                lsum *= corr;
#pragma unroll
                for (int f = 0; f < 4; ++f)
#pragma unroll
                    for (int r = 0; r < 4; ++r) acc[f][r] *= corr;
            }
            float rs = 0.f;
#pragma unroll
            for (int fn = 0; fn < 4; ++fn)
#pragma unroll
                for (int r = 0; r < 4; ++r) {
                    float p = fexp2(s[fn][r] - m);
                    s[fn][r] = p;
                    rs += p;
                }
            lsum += rs;   // per-lane partial; cross-lane reduce deferred
        }

        // P -> Ps[w]: row q=lr, packed b64 per key-block (cvt_pk, RNE)
#pragma unroll
        for (int fn = 0; fn < 4; ++fn) {
            uint2 pk;
            pk.x = pk2bf(s[fn][0], s[fn][1]);
            pk.y = pk2bf(s[fn][2], s[fn][3]);
            *reinterpret_cast<uint2*>((char*)Ps[w] + SWZ(lr, fn * 32 + lk * 8)) = pk;
        }

        // PV swapped: acc[f] += mfma(Vt block f, P^T)
        __builtin_amdgcn_s_setprio(1);
#pragma unroll
        for (int ks = 0; ks < 2; ++ks) {
            const int cb = ks * 64 + lk * 16;
            bf16x8 pa = *reinterpret_cast<const bf16x8*>((char*)Ps[w] + SWZ(lr, cb));
#pragma unroll
            for (int f = 0; f < 4; ++f) {
                bf16x8 vb = *reinterpret_cast<const bf16x8*>(Vs + SWZ(f * 16 + lr, cb));
                acc[f] = __builtin_amdgcn_mfma_f32_16x16x32_bf16(vb, pa, acc[f], 0, 0, 0);
            }
        }
        __builtin_amdgcn_s_setprio(0);
    }

    // epilogue: final cross-lane lsum reduce, then normalize + write planes.
    {
        float ls = lsum;
        ls += __shfl_xor(ls, 16);
        ls += __shfl_xor(ls, 32);
        float inv = 1.f / ls;
        const size_t row = (size_t)(b * LQ + qt * 64 + w * 16 + lr);
#pragma unroll
        for (int f = 0; f < 4; ++f) {
            unsigned short h4[4], l4[4];
#pragma unroll
            for (int r = 0; r < 4; ++r) {
                float x = acc[f][r] * inv;
                h4[r] = f2bf(x);
                l4[r] = f2bf(x - bf2f(h4[r]));
            }
            size_t o = (row << 10) + h * DH + f * 16 + lk * 4;
            *reinterpret_cast<uint2*>(&Ch[o]) = *reinterpret_cast<uint2*>(h4);
            *reinterpret_cast<uint2*>(&Cl[o]) = *reinterpret_cast<uint2*>(l4);
        }
    }
}

extern "C" void kernel_launch(void* const* d_in, const int* in_sizes, int n_in,
                              void* d_out, int out_size, void* d_ws, size_t ws_size,
                              hipStream_t stream)
{
    const float* query = (const float*)d_in[0];
    const float* key   = (const float*)d_in[1];
    const float* value = (const float*)d_in[2];
    const float* Wq = (const float*)d_in[3];
    const float* bq = (const float*)d_in[4];
    const float* Wk = (const float*)d_in[5];
    const float* bk = (const float*)d_in[6];
    const float* Wv = (const float*)d_in[7];
    const float* bv = (const float*)d_in[8];
    const float* Wo = (const float*)d_in[9];
    const float* bo = (const float*)d_in[10];
    float* out = (float*)d_out;

    // ws (88MB): Qh8 | Kh16 | Vth16 | Aq8 | Ak8 | Av8 | Ch8 | Cl8 | W planes 8
    unsigned short* Qh  = (unsigned short*)d_ws;
    unsigned short* Kh  = Qh  + (size_t)4194304;
    unsigned short* Vth = Kh  + (size_t)8388608;
    unsigned short* Aq  = Vth + (size_t)8388608;
    unsigned short* Ak  = Aq  + (size_t)4194304;
    unsigned short* Av  = Ak  + (size_t)4194304;
    unsigned short* Ch  = Av  + (size_t)4194304;
    unsigned short* Cl  = Ch  + (size_t)4194304;
    unsigned short* Wqt = Cl  + (size_t)4194304;
    unsigned short* Wkt = Wqt + (size_t)1048576;
    unsigned short* Wvt = Wkt + (size_t)524288;
    unsigned short* Woh = Wvt + (size_t)524288;
    unsigned short* Wol = Woh + (size_t)1048576;

    // One fused conversion launch + one fused QKV-projection launch
    convert_all<<<15360, 256, 0, stream>>>(query, key, value, Wq, Wk, Wv, Wo,
                                           Aq, Ak, Av, Wqt, Wkt, Wvt, Woh, Wol);
    gemm_qkv<<<1280, 256, 0, stream>>>(Aq, Ak, Av, Wqt, Wkt, Wvt, bq, bk, bv, Qh, Kh, Vth);

    // Attention -> ctx split planes
    attn_mfma<<<LQ / 64 * NH * BB, 256, 0, stream>>>(Qh, Kh, Vth, Ch, Cl);

    // Output projection (3-product split, fp32-grade)
    gemm2<<<(EMB / 128) * (BB * LQ / 128), 256, 0, stream>>>(Ch, Cl, Woh, Wol, bo, out, BB * LQ, EMB, VOUT);
}

// Round 20
// 112.417 us; speedup vs baseline: 1.0284x; 1.0284x over previous
//
#include <hip/hip_runtime.h>
#include <hip/hip_bf16.h>

#define EMB  1024
#define VIN  512
#define VOUT 1024
#define NH   16
#define DH   64
#define BB   8
#define LQ   512
#define LK   1024

typedef __attribute__((ext_vector_type(8))) short bf16x8;
typedef __attribute__((ext_vector_type(4))) float f32x4;

typedef const __attribute__((address_space(1))) unsigned int* gptr_t;
typedef __attribute__((address_space(3))) unsigned int* lptr_t;

__device__ __forceinline__ unsigned short f2bf(float x) {
    unsigned int u = __float_as_uint(x);
    u += 0x7FFF + ((u >> 16) & 1);   // RN-even
    return (unsigned short)(u >> 16);
}
__device__ __forceinline__ float bf2f(unsigned short h) {
    return __uint_as_float(((unsigned int)h) << 16);
}
__device__ __forceinline__ float fexp2(float x) {
    return __builtin_amdgcn_exp2f(x);
}
__device__ __forceinline__ unsigned int pk2bf(float a, float b) {
    float2 f; f.x = a; f.y = b;
    __hip_bfloat162 t = __float22bfloat162_rn(f);   // v_cvt_pk_bf16_f32 (RNE)
    return *reinterpret_cast<unsigned int*>(&t);
}

#define SWZ(row, cb) (((row) << 7) + ((cb) ^ (((row) & 7) << 4)))

// ---------------------------------------------------------------------------
// Fused conversion: blocks 0..12287 = q/k/v fp32->bf16 planes;
// blocks 12288..15359 = weight transpose-split tiles (Wq/Wk/Wv hi; Wo hi+lo).
// ---------------------------------------------------------------------------
__device__ __forceinline__ void wtile(const float* W, unsigned short* Wht,
                                      unsigned short* Wlt, int K, int N,
                                      int bx, int by, int tx, int ty)
{
    __shared__ float t[32][33];
    const int n0 = bx * 32, k0 = by * 32;
#pragma unroll
    for (int r = 0; r < 32; r += 8)
        t[ty + r][tx] = W[(size_t)(k0 + ty + r) * N + n0 + tx];
    __syncthreads();
#pragma unroll
    for (int r = 0; r < 32; r += 8) {
        float x = t[tx][ty + r];
        unsigned short h = f2bf(x);
        size_t o = (size_t)(n0 + ty + r) * K + k0 + tx;
        Wht[o] = h;
        if (Wlt) Wlt[o] = f2bf(x - bf2f(h));
    }
}

__global__ __launch_bounds__(256) void convert_all(const float* __restrict__ q,
                                                   const float* __restrict__ k,
                                                   const float* __restrict__ v,
                                                   const float* __restrict__ Wq,
                                                   const float* __restrict__ Wk,
                                                   const float* __restrict__ Wv,
                                                   const float* __restrict__ Wo,
                                                   unsigned short* __restrict__ Aq,
                                                   unsigned short* __restrict__ Ak,
                                                   unsigned short* __restrict__ Av,
                                                   unsigned short* __restrict__ Wqt,
                                                   unsigned short* __restrict__ Wkt,
                                                   unsigned short* __restrict__ Wvt,
                                                   unsigned short* __restrict__ Woh,
                                                   unsigned short* __restrict__ Wol)
{
    const int id = blockIdx.x;
    if (id < 12288) {
        const int which = id >> 12;
        const float* in = (which == 0) ? q : (which == 1) ? k : v;
        unsigned short* out = (which == 0) ? Aq : (which == 1) ? Ak : Av;
        const int i = (id & 4095) * 256 + threadIdx.x;
        float val[4];
        *reinterpret_cast<float4*>(val) = *reinterpret_cast<const float4*>(&in[(size_t)i * 4]);
        unsigned short h[4];
#pragma unroll
        for (int j = 0; j < 4; ++j) h[j] = f2bf(val[j]);
        *reinterpret_cast<uint2*>(&out[(size_t)i * 4]) = *reinterpret_cast<uint2*>(h);
    } else {
        const int wid = id - 12288;
        const int tx = threadIdx.x & 31, ty = threadIdx.x >> 5;
        if (wid < 1024)      wtile(Wq, Wqt, nullptr, 1024, 1024, wid & 31, wid >> 5, tx, ty);
        else if (wid < 1536) wtile(Wk, Wkt, nullptr, 512, 1024, (wid - 1024) & 31, (wid - 1024) >> 5, tx, ty);
        else if (wid < 2048) wtile(Wv, Wvt, nullptr, 512, 1024, (wid - 1536) & 31, (wid - 1536) >> 5, tx, ty);
        else                 wtile(Wo, Woh, Wol, 1024, 1024, (wid - 2048) & 31, (wid - 2048) >> 5, tx, ty);
    }
}

// ---------------------------------------------------------------------------
// Stage 64x64 of a bf16 plane via global_load_lds (pre-swizzled source).
// ---------------------------------------------------------------------------
__device__ __forceinline__ void stagehalf(const unsigned short* g0, int Kstride,
                                          unsigned short* l0, int lane)
{
#pragma unroll
    for (int r = 0; r < 8; ++r) {
        int row  = r * 8 + (lane >> 3);
        int colb = ((lane & 7) << 4) ^ ((row & 7) << 4);
        const unsigned short* src = g0 + (size_t)row * Kstride + (colb >> 1);
        __builtin_amdgcn_global_load_lds((gptr_t)src, (lptr_t)(l0 + r * 512), 16, 0, 0);
    }
}

// ---------------------------------------------------------------------------
// Fused Q/K/V projection GEMM (plain bf16, double-buffered LDS), one launch.
// seg0: Q (K=1024, out scaled 0.125*log2e); seg1: K; seg2: V transposed.
// seg0/seg1 epilogue via LDS -> coalesced uint4 stores.
// ---------------------------------------------------------------------------
__global__ __launch_bounds__(256, 2) void gemm_qkv(const unsigned short* __restrict__ Aq,
                                                   const unsigned short* __restrict__ Ak,
                                                   const unsigned short* __restrict__ Av,
                                                   const unsigned short* __restrict__ Wqt,
                                                   const unsigned short* __restrict__ Wkt,
                                                   const unsigned short* __restrict__ Wvt,
                                                   const float* __restrict__ bq,
                                                   const float* __restrict__ bk,
                                                   const float* __restrict__ bv,
                                                   unsigned short* __restrict__ Qh,
                                                   unsigned short* __restrict__ Kh,
                                                   unsigned short* __restrict__ Vth)
{
    __shared__ unsigned short As[2][128 * 64], Bs[2][128 * 64];

    const int id  = blockIdx.x;
    const int seg = (id < 256) ? 0 : (id < 768) ? 1 : 2;
    const int lid = id - ((seg == 0) ? 0 : (seg == 1) ? 256 : 768);
    const int nwg = (seg == 0) ? 256 : 512;
    const int K   = (seg == 0) ? 1024 : 512;
    const unsigned short* Ah  = (seg == 0) ? Aq : (seg == 1) ? Ak : Av;
    const unsigned short* Bht = (seg == 0) ? Wqt : (seg == 1) ? Wkt : Wvt;
    const float* bias = (seg == 0) ? bq : (seg == 1) ? bk : bv;
    unsigned short* Ch = (seg == 0) ? Qh : (seg == 1) ? Kh : Vth;
    const int N = 1024;

    const int qq  = nwg >> 3;
    const int swz = (lid & 7) * qq + (lid >> 3);   // seg-local XCD swizzle
    const int bx = swz & 7, by = swz >> 3;         // nbx = 8
    const int m0 = by * 128, n0 = bx * 128;

    const int tid  = threadIdx.x;
    const int lane = tid & 63;
    const int w    = tid >> 6;
    const int wm = (w & 1) * 64;
    const int wn = (w >> 1) * 64;
    const int lr = lane & 15;
    const int lk = lane >> 4;

    f32x4 acc[4][4];
#pragma unroll
    for (int i = 0; i < 4; ++i)
#pragma unroll
        for (int j = 0; j < 4; ++j) acc[i][j] = (f32x4)(0.f);

    const unsigned short* mysrc = (w < 2)
        ? Ah  + (size_t)(m0 + (w & 1) * 64) * K
        : Bht + (size_t)(n0 + (w & 1) * 64) * K;
    const int lofs = (w & 1) * 4096;
    unsigned short* pl0 = ((w < 2) ? As[0] : Bs[0]) + lofs;
    unsigned short* pl1 = ((w < 2) ? As[1] : Bs[1]) + lofs;

    stagehalf(mysrc, K, pl0, lane);

    const int nt = K >> 6;
    for (int t = 0; t < nt; ++t) {
        __syncthreads();
        if (t + 1 < nt)
            stagehalf(mysrc + ((size_t)(t + 1) << 6), K, ((t & 1) ? pl0 : pl1), lane);

        const char* Ac = (const char*)As[t & 1];
        const char* Bc = (const char*)Bs[t & 1];
#pragma unroll
        for (int ks = 0; ks < 2; ++ks) {
            bf16x8 ah[4], bh[4];
            const int cb = ks * 64 + lk * 16;
#pragma unroll
            for (int f = 0; f < 4; ++f) {
                ah[f] = *reinterpret_cast<const bf16x8*>(Ac + SWZ(wm + f * 16 + lr, cb));
                bh[f] = *reinterpret_cast<const bf16x8*>(Bc + SWZ(wn + f * 16 + lr, cb));
            }
#pragma unroll
            for (int fm = 0; fm < 4; ++fm)
#pragma unroll
                for (int fn = 0; fn < 4; ++fn)
                    acc[fm][fn] = __builtin_amdgcn_mfma_f32_16x16x32_bf16(ah[fm], bh[fn], acc[fm][fn], 0, 0, 0);
        }
    }

    if (seg != 2) {
        // -------- LDS-transpose epilogue: coalesced uint4 stores ----------
        __syncthreads();   // compute done; reuse staging LDS
        const float sc = (seg == 0) ? 0.18033688011112042f : 1.0f;
#pragma unroll
        for (int fn = 0; fn < 4; ++fn) {
            const int col = wn + fn * 16 + lr;
            const float bv_ = bias[n0 + col];
#pragma unroll
            for (int fm = 0; fm < 4; ++fm) {
                const int row0 = wm + fm * 16 + lk * 4;
#pragma unroll
                for (int r = 0; r < 4; ++r) {
                    int row = row0 + r;
                    unsigned short* base = (row < 64) ? ((row < 32) ? As[0] : As[1])
                                                      : ((row < 96) ? Bs[0] : Bs[1]);
                    base[(row & 31) * 136 + col] = f2bf((acc[fm][fn][r] + bv_) * sc);
                }
            }
        }
        __syncthreads();
#pragma unroll
        for (int rnd = 0; rnd < 8; ++rnd) {
            int flat = rnd * 256 + tid;
            int row  = flat >> 4;
            int c16  = flat & 15;
            const unsigned short* base = (row < 64) ? ((row < 32) ? As[0] : As[1])
                                                    : ((row < 96) ? Bs[0] : Bs[1]);
            uint4 vv = *reinterpret_cast<const uint4*>(&base[(row & 31) * 136 + c16 * 8]);
            *reinterpret_cast<uint4*>(&Ch[(size_t)(m0 + row) * N + n0 + c16 * 8]) = vv;
        }
    } else {
        // -------- V: per-head transposed, already 8B-packed ----------------
#pragma unroll
        for (int fn = 0; fn < 4; ++fn) {
            const int col = n0 + wn + fn * 16 + lr;
            const float bv_ = bias[col];
#pragma unroll
            for (int fm = 0; fm < 4; ++fm) {
                const int row0 = m0 + wm + fm * 16 + lk * 4;
                unsigned short h4[4];
#pragma unroll
                for (int r = 0; r < 4; ++r)
                    h4[r] = f2bf(acc[fm][fn][r] + bv_);
                size_t o = (((size_t)((row0 >> 10) * NH + (col >> 6)) * 64 + (col & 63)) << 10) + (row0 & 1023);
                *reinterpret_cast<uint2*>(&Ch[o]) = *reinterpret_cast<uint2*>(h4);
            }
        }
    }
}

// ---------------------------------------------------------------------------
// Stage one 128-row x 64-col plane tile (gemm2, BK=64).
// ---------------------------------------------------------------------------
__device__ __forceinline__ void stageplane(const unsigned short* g0, int Kstride,
                                           unsigned short* l0, int lane)
{
#pragma unroll
    for (int r = 0; r < 16; ++r) {
        int row  = r * 8 + (lane >> 3);
        int colb = ((lane & 7) << 4) ^ ((row & 7) << 4);
        const unsigned short* src = g0 + (size_t)row * Kstride + (colb >> 1);
        __builtin_amdgcn_global_load_lds((gptr_t)src, (lptr_t)(l0 + r * 512), 16, 0, 0);
    }
}

// ---------------------------------------------------------------------------
// Split-bf16 MFMA GEMM (3 products) — O-projection, fp32 out, double-buffered
// BK=64 (R18 proven version).
// ---------------------------------------------------------------------------
__global__ __launch_bounds__(256) void gemm2(const unsigned short* __restrict__ Ah,
                                             const unsigned short* __restrict__ Al,
                                             const unsigned short* __restrict__ Bht,
                                             const unsigned short* __restrict__ Blt,
                                             const float* __restrict__ bias,
                                             float* __restrict__ C,
                                             int M, int N, int K)
{
    __shared__ unsigned short As_h[2][128 * 64], As_l[2][128 * 64];
    __shared__ unsigned short Bs_h[2][128 * 64], Bs_l[2][128 * 64];

    const int nbx = N >> 7;
    const int nwg = gridDim.x;
    const int qq  = nwg >> 3;
    const int id  = blockIdx.x;
    const int swz = (id & 7) * qq + (id >> 3);
    const int bx = swz % nbx, by = swz / nbx;
    const int m0 = by * 128, n0 = bx * 128;

    const int tid  = threadIdx.x;
    const int lane = tid & 63;
    const int w    = tid >> 6;
    const int wm = (w & 1) * 64;
    const int wn = (w >> 1) * 64;
    const int lr = lane & 15;
    const int lk = lane >> 4;

    f32x4 acc[4][4];
#pragma unroll
    for (int i = 0; i < 4; ++i)
#pragma unroll
        for (int j = 0; j < 4; ++j) acc[i][j] = (f32x4)(0.f);

    const unsigned short* mysrc =
        (w == 0) ? Ah + (size_t)m0 * K :
        (w == 1) ? Al + (size_t)m0 * K :
        (w == 2) ? Bht + (size_t)n0 * K :
                   Blt + (size_t)n0 * K;
    unsigned short* pl0 = (w == 0) ? As_h[0] : (w == 1) ? As_l[0] : (w == 2) ? Bs_h[0] : Bs_l[0];
    unsigned short* pl1 = (w == 0) ? As_h[1] : (w == 1) ? As_l[1] : (w == 2) ? Bs_h[1] : Bs_l[1];

    stageplane(mysrc, K, pl0, lane);

    const int nt = K >> 6;
    for (int t = 0; t < nt; ++t) {
        __syncthreads();
        if (t + 1 < nt)
            stageplane(mysrc + ((size_t)(t + 1) << 6), K, ((t & 1) ? pl0 : pl1), lane);

        const char* Ahc = (const char*)As_h[t & 1];
        const char* Alc = (const char*)As_l[t & 1];
        const char* Bhc = (const char*)Bs_h[t & 1];
        const char* Blc = (const char*)Bs_l[t & 1];
#pragma unroll
        for (int ks = 0; ks < 2; ++ks) {
            bf16x8 ah[4], al[4], bh[4], bl[4];
            const int cb = ks * 64 + lk * 16;
#pragma unroll
            for (int f = 0; f < 4; ++f) {
                int rowA = wm + f * 16 + lr;
                ah[f] = *reinterpret_cast<const bf16x8*>(Ahc + SWZ(rowA, cb));
                al[f] = *reinterpret_cast<const bf16x8*>(Alc + SWZ(rowA, cb));
                int rowB = wn + f * 16 + lr;
                bh[f] = *reinterpret_cast<const bf16x8*>(Bhc + SWZ(rowB, cb));
                bl[f] = *reinterpret_cast<const bf16x8*>(Blc + SWZ(rowB, cb));
            }
#pragma unroll
            for (int fm = 0; fm < 4; ++fm)
#pragma unroll
                for (int fn = 0; fn < 4; ++fn) {
                    acc[fm][fn] = __builtin_amdgcn_mfma_f32_16x16x32_bf16(ah[fm], bh[fn], acc[fm][fn], 0, 0, 0);
                    acc[fm][fn] = __builtin_amdgcn_mfma_f32_16x16x32_bf16(ah[fm], bl[fn], acc[fm][fn], 0, 0, 0);
                    acc[fm][fn] = __builtin_amdgcn_mfma_f32_16x16x32_bf16(al[fm], bh[fn], acc[fm][fn], 0, 0, 0);
                }
        }
    }

#pragma unroll
    for (int fn = 0; fn < 4; ++fn) {
        const int col = n0 + wn + fn * 16 + lr;
        const float bv = bias[col];
#pragma unroll
        for (int fm = 0; fm < 4; ++fm) {
            const int row0 = m0 + wm + fm * 16 + lk * 4;
#pragma unroll
            for (int r = 0; r < 4; ++r)
                C[(size_t)(row0 + r) * N + col] = acc[fm][fn][r] + bv;
        }
    }
}

// ---------------------------------------------------------------------------
// Stage 32 rows x 128B (row stride 1024 elems), pre-swizzled source.
// ---------------------------------------------------------------------------
__device__ __forceinline__ void stage32(const unsigned short* g0, unsigned short* l0, int lane)
{
#pragma unroll
    for (int r = 0; r < 4; ++r) {
        int row  = r * 8 + (lane >> 3);
        int colb = ((lane & 7) << 4) ^ ((row & 7) << 4);
        const unsigned short* src = g0 + ((size_t)row << 10) + (colb >> 1);
        __builtin_amdgcn_global_load_lds((gptr_t)src, (lptr_t)(l0 + r * 512), 16, 0, 0);
    }
}

// ---------------------------------------------------------------------------
// MFMA flash attention (R18 structure, m=0 init kept from R19 — measured
// neutral/slightly positive).
// ---------------------------------------------------------------------------
__global__ __launch_bounds__(256, 4) void attn_mfma(const unsigned short* __restrict__ Qh,
                                                    const unsigned short* __restrict__ Kh,
                                                    const unsigned short* __restrict__ Vth,
                                                    unsigned short* __restrict__ Ch,
                                                    unsigned short* __restrict__ Cl)
{
    const int id  = blockIdx.x;
    const int qt  = (id >> 3) & 7;
    const int grp = (id & 7) | ((id >> 6) << 3);   // 0..127, same-XCD groups
    const int h = grp & 15, b = grp >> 4;

    const int tid  = threadIdx.x;
    const int lane = tid & 63;
    const int w    = tid >> 6;
    const int lr   = lane & 15;
    const int lk   = lane >> 4;

    __shared__ unsigned short KVs[2][2][4096];
    __shared__ unsigned short Ps[4][1024];

    bf16x8 qb[2];
    {
        const unsigned short* qrow = &Qh[(size_t)(b * LQ + qt * 64 + w * 16 + lr) * EMB + h * DH];
        qb[0] = *reinterpret_cast<const bf16x8*>(qrow + lk * 8);
        qb[1] = *reinterpret_cast<const bf16x8*>(qrow + 32 + lk * 8);
    }

    const unsigned short* K0 = Kh + ((size_t)(b * LK) << 10) + h * DH;
    const unsigned short* V0 = Vth + ((size_t)(grp * 64) << 10);

    {
        const int half = (w & 1) * 32;
        if (w < 2) stage32(K0 + ((size_t)half << 10), KVs[0][0] + half * 64, lane);
        else       stage32(V0 + ((size_t)half << 10), KVs[0][1] + half * 64, lane);
    }

    float m = 0.f, lsum = 0.f;   // m=0 init (rescale path retained)
    f32x4 acc[4];
#pragma unroll
    for (int f = 0; f < 4; ++f) acc[f] = (f32x4)(0.f);

    for (int kt = 0; kt < LK / 64; ++kt) {
        const int cur = kt & 1;
        __syncthreads();

        if (kt + 1 < LK / 64) {
            const size_t koff = (size_t)(kt + 1) * 64;
            const int half = (w & 1) * 32;
            if (w < 2) stage32(K0 + ((koff + half) << 10), KVs[cur ^ 1][0] + half * 64, lane);
            else       stage32(V0 + ((size_t)half << 10) + koff, KVs[cur ^ 1][1] + half * 64, lane);
        }

        const char* Ks = (const char*)KVs[cur][0];
        const char* Vs = (const char*)KVs[cur][1];

        f32x4 s[4];
#pragma unroll
        for (int fn = 0; fn < 4; ++fn) s[fn] = (f32x4)(0.f);
        __builtin_amdgcn_s_setprio(1);
#pragma unroll
        for (int ks = 0; ks < 2; ++ks) {
            const int cb = ks * 64 + lk * 16;
#pragma unroll
            for (int fn = 0; fn < 4; ++fn) {
                bf16x8 kb = *reinterpret_cast<const bf16x8*>(Ks + SWZ(fn * 16 + lr, cb));
                s[fn] = __builtin_amdgcn_mfma_f32_16x16x32_bf16(kb, qb[ks], s[fn], 0, 0, 0);
            }
        }
        __builtin_amdgcn_s_setprio(0);

        // online softmax, lane-local row q = lr; gated defer-max (THR=8)
        {
            f32x4 t4 = s[0];
#pragma unroll
            for (int fn = 1; fn < 4; ++fn)
#pragma unroll
                for (int r = 0; r < 4; ++r) t4[r] = fmaxf(t4[r], s[fn][r]);
            float lmx = fmaxf(fmaxf(t4[0], t4[1]), fmaxf(t4[2], t4[3]));

            if (!__all(lmx <= m + 8.f)) {
                float mx = fmaxf(lmx, __shfl_xor(lmx, 16));
                mx = fmaxf(mx, __shfl_xor(mx, 32));
                float mnew = fmaxf(m, mx);
                float corr = fexp2(m - mnew);
                m = mnew;
                lsum *= corr;
#pragma unroll
                for (int f = 0; f < 4; ++f)
#pragma unroll
                    for (int r = 0; r < 4; ++r) acc[f][r] *= corr;
            }
            float rs = 0.f;
#pragma unroll
            for (int fn = 0; fn < 4; ++fn)
#pragma unroll
                for (int r = 0; r < 4; ++r) {
                    float p = fexp2(s[fn][r] - m);
                    s[fn][r] = p;
                    rs += p;
                }
            lsum += rs;   // per-lane partial; cross-lane reduce deferred
        }

        // P -> Ps[w]: row q=lr, packed b64 per key-block (cvt_pk, RNE)
#pragma unroll
        for (int fn = 0; fn < 4; ++fn) {
            uint2 pk;
            pk.x = pk2bf(s[fn][0], s[fn][1]);
            pk.y = pk2bf(s[fn][2], s[fn][3]);
            *reinterpret_cast<uint2*>((char*)Ps[w] + SWZ(lr, fn * 32 + lk * 8)) = pk;
        }

        // PV swapped: acc[f] += mfma(Vt block f, P^T)
        __builtin_amdgcn_s_setprio(1);
#pragma unroll
        for (int ks = 0; ks < 2; ++ks) {
            const int cb = ks * 64 + lk * 16;
            bf16x8 pa = *reinterpret_cast<const bf16x8*>((char*)Ps[w] + SWZ(lr, cb));
#pragma unroll
            for (int f = 0; f < 4; ++f) {
                bf16x8 vb = *reinterpret_cast<const bf16x8*>(Vs + SWZ(f * 16 + lr, cb));
                acc[f] = __builtin_amdgcn_mfma_f32_16x16x32_bf16(vb, pa, acc[f], 0, 0, 0);
            }
        }
        __builtin_amdgcn_s_setprio(0);
    }

    // epilogue: final cross-lane lsum reduce, then normalize + write planes.
    {
        float ls = lsum;
        ls += __shfl_xor(ls, 16);
        ls += __shfl_xor(ls, 32);
        float inv = 1.f / ls;
        const size_t row = (size_t)(b * LQ + qt * 64 + w * 16 + lr);
#pragma unroll
        for (int f = 0; f < 4; ++f) {
            unsigned short h4[4], l4[4];
#pragma unroll
            for (int r = 0; r < 4; ++r) {
                float x = acc[f][r] * inv;
                h4[r] = f2bf(x);
                l4[r] = f2bf(x - bf2f(h4[r]));
            }
            size_t o = (row << 10) + h * DH + f * 16 + lk * 4;
            *reinterpret_cast<uint2*>(&Ch[o]) = *reinterpret_cast<uint2*>(h4);
            *reinterpret_cast<uint2*>(&Cl[o]) = *reinterpret_cast<uint2*>(l4);
        }
    }
}

extern "C" void kernel_launch(void* const* d_in, const int* in_sizes, int n_in,
                              void* d_out, int out_size, void* d_ws, size_t ws_size,
                              hipStream_t stream)
{
    const float* query = (const float*)d_in[0];
    const float* key   = (const float*)d_in[1];
    const float* value = (const float*)d_in[2];
    const float* Wq = (const float*)d_in[3];
    const float* bq = (const float*)d_in[4];
    const float* Wk = (const float*)d_in[5];
    const float* bk = (const float*)d_in[6];
    const float* Wv = (const float*)d_in[7];
    const float* bv = (const float*)d_in[8];
    const float* Wo = (const float*)d_in[9];
    const float* bo = (const float*)d_in[10];
    float* out = (float*)d_out;

    // ws (88MB): Qh8 | Kh16 | Vth16 | Aq8 | Ak8 | Av8 | Ch8 | Cl8 | W planes 8
    unsigned short* Qh  = (unsigned short*)d_ws;
    unsigned short* Kh  = Qh  + (size_t)4194304;
    unsigned short* Vth = Kh  + (size_t)8388608;
    unsigned short* Aq  = Vth + (size_t)8388608;
    unsigned short* Ak  = Aq  + (size_t)4194304;
    unsigned short* Av  = Ak  + (size_t)4194304;
    unsigned short* Ch  = Av  + (size_t)4194304;
    unsigned short* Cl  = Ch  + (size_t)4194304;
    unsigned short* Wqt = Cl  + (size_t)4194304;
    unsigned short* Wkt = Wqt + (size_t)1048576;
    unsigned short* Wvt = Wkt + (size_t)524288;
    unsigned short* Woh = Wvt + (size_t)524288;
    unsigned short* Wol = Woh + (size_t)1048576;

    // One fused conversion launch + one fused QKV-projection launch
    convert_all<<<15360, 256, 0, stream>>>(query, key, value, Wq, Wk, Wv, Wo,
                                           Aq, Ak, Av, Wqt, Wkt, Wvt, Woh, Wol);
    gemm_qkv<<<1280, 256, 0, stream>>>(Aq, Ak, Av, Wqt, Wkt, Wvt, bq, bk, bv, Qh, Kh, Vth);

    // Attention -> ctx split planes
    attn_mfma<<<LQ / 64 * NH * BB, 256, 0, stream>>>(Qh, Kh, Vth, Ch, Cl);

    // Output projection (3-product split, fp32-grade)
    gemm2<<<(EMB / 128) * (BB * LQ / 128), 256, 0, stream>>>(Ch, Cl, Woh, Wol, bo, out, BB * LQ, EMB, VOUT);
}